// Round 12
// baseline (306.186 us; speedup 1.0000x reference)
//
#include <hip/hip_runtime.h>
#include <stdint.h>

typedef __attribute__((ext_vector_type(8))) short short8;
typedef __attribute__((ext_vector_type(4))) float f32x4;
typedef __attribute__((ext_vector_type(16))) float f32x16;

#define MFMA16(A_, B_, C_) __builtin_amdgcn_mfma_f32_16x16x32_bf16((A_), (B_), (C_), 0, 0, 0)
#define MFMA32(A_, B_, C_) __builtin_amdgcn_mfma_f32_32x32x16_bf16((A_), (B_), (C_), 0, 0, 0)

#if __has_builtin(__builtin_amdgcn_exp2f)
#define EXP2(x) __builtin_amdgcn_exp2f(x)
#else
#define EXP2(x) exp2f(x)
#endif

// async global -> LDS, 16B per lane (dest = wave-uniform base + lane*16)
#define GLDS16(g_, l_)                                                        \
  __builtin_amdgcn_global_load_lds(                                           \
      (const __attribute__((address_space(1))) void*)(g_),                    \
      (__attribute__((address_space(3))) void*)(l_), 16, 0, 0)

__device__ __forceinline__ unsigned short f2bf(float f) {
  unsigned int u = __float_as_uint(f);
  u += 0x7fffu + ((u >> 16) & 1u);
  return (unsigned short)(u >> 16);
}

// pack two f32 -> two truncated bf16 in one u32 (a -> low, b -> high)
__device__ __forceinline__ unsigned pk2(float a, float b) {
  return (__float_as_uint(a) >> 16) | (__float_as_uint(b) & 0xffff0000u);
}

// ---------------- prep kernels ----------------

// 32B per thread: 8 floats -> 8 bf16 (RNE)
__global__ void cast_x_kernel(const float* __restrict__ x,
                              unsigned short* __restrict__ xb, int n8) {
  int i = blockIdx.x * blockDim.x + threadIdx.x;
  if (i >= n8) return;
  const float4* x4 = reinterpret_cast<const float4*>(x);
  float4 a = x4[2 * i], b = x4[2 * i + 1];
  uint4 o;
  o.x = (unsigned)f2bf(a.x) | ((unsigned)f2bf(a.y) << 16);
  o.y = (unsigned)f2bf(a.z) | ((unsigned)f2bf(a.w) << 16);
  o.z = (unsigned)f2bf(b.x) | ((unsigned)f2bf(b.y) << 16);
  o.w = (unsigned)f2bf(b.z) | ((unsigned)f2bf(b.w) << 16);
  reinterpret_cast<uint4*>(xb)[i] = o;
}

// Wt[n][k] = bf16(W[k][n]) for 4 weight matrices (blockIdx.z selects)
__global__ void transpose_cast4_kernel(const float* __restrict__ W0,
                                       const float* __restrict__ W1,
                                       const float* __restrict__ W2,
                                       const float* __restrict__ W3,
                                       unsigned short* __restrict__ T0,
                                       unsigned short* __restrict__ T1,
                                       unsigned short* __restrict__ T2,
                                       unsigned short* __restrict__ T3) {
  __shared__ float tile[32][33];
  const float* W = (blockIdx.z == 0) ? W0 : (blockIdx.z == 1) ? W1
                   : (blockIdx.z == 2) ? W2 : W3;
  unsigned short* Wt = (blockIdx.z == 0) ? T0 : (blockIdx.z == 1) ? T1
                       : (blockIdx.z == 2) ? T2 : T3;
  int k0 = blockIdx.x * 32, n0 = blockIdx.y * 32;
  int tx = threadIdx.x, ty = threadIdx.y;  // 32 x 8
  for (int i = ty; i < 32; i += 8)
    tile[i][tx] = W[(size_t)(k0 + i) * 1024 + n0 + tx];
  __syncthreads();
  for (int i = ty; i < 32; i += 8)
    Wt[(size_t)(n0 + i) * 1024 + k0 + tx] = f2bf(tile[tx][i]);
}

// ---------------- GEMM: 256x256 tile, BK=64, 8 waves, counted-vmcnt pipeline
// (r10-proven staging/sync; compute switched to mfma_f32_32x32x16_bf16)
// MODE 0: Q (scale by 0.125*log2e, store [b][s][h][r][d]); A = Xb [16384][1024]
// MODE 1: K (store [b][s][h][r][d]);                       A = Xb
// MODE 2: V (store Vt [b][s][h][d][r'] col-permuted + Vtd); A = Xb
// MODE 3: O (store f32 row-major to d_out); A = AO2 head-major [b][s][h][q][d]
//         (BK=64 == DK, so K-step kt == head index)
// LDS layout: [buf][row][chunk], 16B chunk c holds global chunk c ^ (row&7).
// 32x32x16 fragments: A/B lane: row/col = lane&31, k = (lane>>5)*8 + e.
// C/D (HW-verified m74/m101): col = lane&31, row = (reg&3)+8*(reg>>2)+4*(lane>>5).
template<int MODE>
__global__ __launch_bounds__(512, 2) void gemm_kernel(
    const unsigned short* __restrict__ A,
    const unsigned short* __restrict__ W,
    const float* __restrict__ bias,
    unsigned short* __restrict__ out_bf,
    unsigned short* __restrict__ out_vtd,
    float* __restrict__ out_f) {
  __shared__ unsigned short Asm[2][256 * 64];  // 64 KiB
  __shared__ unsigned short Bsm[2][256 * 64];  // 64 KiB
  const int t = threadIdx.x;
  // XCD-bijective swizzle (nwg = 256, %8 == 0)
  const int wg = (blockIdx.x & 7) * 32 + (blockIdx.x >> 3);
  const int m0 = (wg >> 2) * 256;
  const int n0 = (wg & 3) * 256;
  const int w = t >> 6, lane = t & 63;
  const int wm = w >> 2, wn = w & 3;  // 2 x 4 wave grid; per-wave out 128x64
  const int rl = lane & 31, l5 = lane >> 5;

  f32x16 acc[4][2];
#pragma unroll
  for (int i = 0; i < 4; ++i)
#pragma unroll
    for (int j = 0; j < 2; ++j)
#pragma unroll
      for (int e = 0; e < 16; ++e) acc[i][j][e] = 0.f;

  // staging: wave w stages rows w*32 .. w*32+31 of both tiles.
  // lane -> row w*32 + p*8 + (lane>>3), source chunk = (lane&7) ^ (lane>>3).
  const int srow = lane >> 3;
  const int sswz = ((lane & 7) ^ srow) * 8;
  const int mrow = m0 + w * 32 + srow;
  const unsigned short* gA;
  size_t astep, arstride;  // per-kt advance, per-8-row advance
  if (MODE == 3) {
    // AO2 head-major: m = b*8192 + s*512 + q  ->  head base (m>>9), q = m&511
    gA = A + (size_t)(mrow >> 9) * (16 * 32768) + (size_t)(mrow & 511) * 64 + sswz;
    astep = 32768;       // next head
    arstride = 8 * 64;   // +8 q rows
  } else {
    gA = A + (size_t)mrow * 1024 + sswz;
    astep = 64;          // next 64 k-columns
    arstride = 8 * 1024; // +8 m rows
  }
  const unsigned short* gB = W + (size_t)(n0 + w * 32 + srow) * 1024 + sswz;

  auto stage = [&](int buf, int kt) {
    const unsigned short* ga = gA + (size_t)kt * astep;
    const unsigned short* gb = gB + (size_t)kt * 64;
    unsigned short* la = &Asm[buf][(w * 32) * 64];
    unsigned short* lb = &Bsm[buf][(w * 32) * 64];
#pragma unroll
    for (int p = 0; p < 4; ++p) {
      GLDS16(ga + (size_t)p * arstride, la + p * 8 * 64);
      GLDS16(gb + (size_t)(p * 8) * 1024, lb + p * 8 * 64);
    }
  };

  const int rswz = (rl & 7);  // read-side swizzle term (row&7)
  auto compute = [&](int buf) {
    const unsigned short* bA = &Asm[buf][0];
    const unsigned short* bB = &Bsm[buf][0];
    short8 bfv[4][2];
#pragma unroll
    for (int ks = 0; ks < 4; ++ks)
#pragma unroll
      for (int j = 0; j < 2; ++j) {
        const int row = wn * 64 + j * 32 + rl;
        bfv[ks][j] = *reinterpret_cast<const short8*>(
            &bB[row * 64 + (((ks * 2 + l5) ^ rswz) * 8)]);
      }
#pragma unroll
    for (int i = 0; i < 4; ++i) {
      const int row = wm * 128 + i * 32 + rl;
      short8 af[4];
#pragma unroll
      for (int ks = 0; ks < 4; ++ks)
        af[ks] = *reinterpret_cast<const short8*>(
            &bA[row * 64 + (((ks * 2 + l5) ^ rswz) * 8)]);
#pragma unroll
      for (int ks = 0; ks < 4; ++ks)
#pragma unroll
        for (int j = 0; j < 2; ++j)
          acc[i][j] = MFMA32(af[ks], bfv[ks][j], acc[i][j]);
    }
  };

  stage(0, 0);
#pragma unroll 1
  for (int kt = 0; kt < 15; ++kt) {
    stage((kt + 1) & 1, kt + 1);
    // own step-kt loads done; step-(kt+1)'s 8 stay in flight across barrier
    asm volatile("s_waitcnt vmcnt(8)\n\ts_barrier" ::: "memory");
    compute(kt & 1);
    asm volatile("s_waitcnt lgkmcnt(0)\n\ts_barrier" ::: "memory");
  }
  asm volatile("s_waitcnt vmcnt(0)\n\ts_barrier" ::: "memory");
  compute(1);  // kt = 15

  // epilogue: 32x32 C/D mapping — col = rl, row = (reg&3)+8*(reg>>2)+4*l5
#pragma unroll
  for (int i = 0; i < 4; ++i)
#pragma unroll
    for (int j = 0; j < 2; ++j) {
      const int n = n0 + wn * 64 + j * 32 + rl;
      const float bv = bias[n];
#pragma unroll
      for (int reg = 0; reg < 16; ++reg) {
        const int m = m0 + wm * 128 + i * 32 + (reg & 3) + 8 * (reg >> 2) + 4 * l5;
        float val = acc[i][j][reg] + bv;
        if (MODE == 3) {
          out_f[(size_t)m * 1024 + n] = val;
        } else {
          const int b = m >> 13, ll = m & 8191;
          const int ss = ll >> 9, rr = ll & 511;
          const int hh = n >> 6, d = n & 63;
          const size_t head = (size_t)((b * 16 + ss) * 16 + hh);
          if (MODE == 0) {
            out_bf[head * 32768 + rr * 64 + d] = f2bf(val * 0.18033688011112042f);
          } else if (MODE == 1) {
            out_bf[head * 32768 + rr * 64 + d] = f2bf(val);
          } else {
            // column-permute within each 32-block: k = g*16+q*4+m -> pos = q*8+g*4+m
            const int p32 = (((rr >> 2) & 3) << 3) | (((rr >> 4) & 1) << 2) | (rr & 3);
            out_bf[head * 32768 + (size_t)d * 512 + ((rr & ~31) | p32)] = f2bf(val);
            if ((rr & 3) == 0) {
              const int cd = rr >> 2;
              const int pd = (((cd >> 2) & 3) << 3) | (((cd >> 4) & 1) << 2) | (cd & 3);
              out_vtd[head * 8192 + (size_t)d * 128 + ((cd & ~31) | pd)] = f2bf(val);
            }
          }
        }
      }
    }
}

// ---------------- attention ----------------
// r10-proven: grid 1024, 8 waves x 32 q-rows; q-halves of a head paired onto
// the SAME XCD (qh = wg>>9; 512 % 8 == 0) for K/V L2 sharing.
// Swapped QK^T (lane holds P[q=lr][k]), in-register P pack, permuted-k-slot PV.
// K/V chunk tiles (64x64 bf16) staged cooperatively (1 GLDS16 per wave each),
// double-buffered; __syncthreads() drains prefetch + protects buffer swap.
// Bank swizzle: LDS[row][c'] = G[row][c' ^ (row&7)] via pre-swizzled global
// source; reads XOR the same term (lr&7, lane-constant).
__device__ __forceinline__ void attn_group(
    const unsigned short* __restrict__ Kp, int kstride,   // 64 (self) / 256 (dil)
    const unsigned short* __restrict__ Vp, int vstride,   // 512 (self) / 128 (dil)
    int nchunks, float wgt,
    const short8 (&qf)[2][2],
    unsigned short* __restrict__ Kl, unsigned short* __restrict__ Vl,  // [2][4096]
    f32x4 (&total)[2][4],
    int lr, int lg, int w, int lane) {
  const int srow = lane >> 3;             // 0..7
  const int fcw = (lane & 7) ^ srow;      // swizzled fetch chunk
  const unsigned short* gK = Kp + (size_t)(w * 8 + srow) * kstride + fcw * 8;
  const unsigned short* gV = Vp + (size_t)(w * 8 + srow) * vstride + fcw * 8;
  const int sx = lr & 7;                  // read-side swizzle (chunks)

  float l[2][2] = {{0.f, 0.f}, {0.f, 0.f}};
  f32x4 acc[2][4];
#pragma unroll
  for (int rt = 0; rt < 2; ++rt)
#pragma unroll
    for (int dt = 0; dt < 4; ++dt) acc[rt][dt] = f32x4{0.f, 0.f, 0.f, 0.f};

  // prologue: stage chunk 0 -> buf 0
  GLDS16(gK, Kl + w * 512);
  GLDS16(gV, Vl + w * 512);
  __syncthreads();  // drains vmcnt(0): chunk 0 visible to all waves

  int cur = 0;
  for (int c = 0; c < nchunks; ++c) {
    if (c + 1 < nchunks) {  // prefetch next chunk into other buffer
      GLDS16(gK + (size_t)((c + 1) * 64) * kstride, Kl + (cur ^ 1) * 4096 + w * 512);
      GLDS16(gV + (c + 1) * 64, Vl + (cur ^ 1) * 4096 + w * 512);
    }
    const unsigned short* bK = Kl + cur * 4096;
    const unsigned short* bV = Vl + cur * 4096;

    short8 pf[2][2];
    // QK in kt-pairs (kp = ks of PV); sc live range = 16 regs
#pragma unroll
    for (int kp = 0; kp < 2; ++kp) {
      f32x4 s0[2], s1[2];
#pragma unroll
      for (int rt = 0; rt < 2; ++rt) {
        s0[rt] = f32x4{0.f, 0.f, 0.f, 0.f};
        s1[rt] = f32x4{0.f, 0.f, 0.f, 0.f};
      }
      __builtin_amdgcn_s_setprio(1);
#pragma unroll
      for (int ks = 0; ks < 2; ++ks) {
        const int rc = (((ks * 4 + lg) ^ sx) * 8);
        short8 kf0 = *reinterpret_cast<const short8*>(&bK[(kp * 32 + lr) * 64 + rc]);
        short8 kf1 = *reinterpret_cast<const short8*>(&bK[(kp * 32 + 16 + lr) * 64 + rc]);
#pragma unroll
        for (int rt = 0; rt < 2; ++rt) {
          s0[rt] = MFMA16(kf0, qf[rt][ks], s0[rt]);
          s1[rt] = MFMA16(kf1, qf[rt][ks], s1[rt]);
        }
      }
      __builtin_amdgcn_s_setprio(0);
#pragma unroll
      for (int rt = 0; rt < 2; ++rt) {
        float e0 = EXP2(s0[rt][0]), e1 = EXP2(s0[rt][1]);
        float e2 = EXP2(s0[rt][2]), e3 = EXP2(s0[rt][3]);
        float e4 = EXP2(s1[rt][0]), e5 = EXP2(s1[rt][1]);
        float e6 = EXP2(s1[rt][2]), e7 = EXP2(s1[rt][3]);
        l[rt][kp] += ((e0 + e1) + (e2 + e3)) + ((e4 + e5) + (e6 + e7));
        uint4 wv;
        wv.x = pk2(e0, e1); wv.y = pk2(e2, e3);
        wv.z = pk2(e4, e5); wv.w = pk2(e6, e7);
        pf[rt][kp] = *reinterpret_cast<short8*>(&wv);
      }
    }
    // PV (V columns pre-permuted at GEMM store -> 16B contiguous fragments)
    __builtin_amdgcn_s_setprio(1);
#pragma unroll
    for (int ks = 0; ks < 2; ++ks) {
      const int rcv = (((ks * 4 + lg) ^ sx) * 8);
#pragma unroll
      for (int dt = 0; dt < 4; ++dt) {
        short8 vf = *reinterpret_cast<const short8*>(&bV[(dt * 16 + lr) * 64 + rcv]);
#pragma unroll
        for (int rt = 0; rt < 2; ++rt)
          acc[rt][dt] = MFMA16(pf[rt][ks], vf, acc[rt][dt]);
      }
    }
    __builtin_amdgcn_s_setprio(0);
    __syncthreads();  // drains prefetch (vmcnt 0) + protects buffer swap
    cur ^= 1;
  }
  // finalize: l full sum at q=lr; acc rows q=lg*4+r -> transpose l via shfl
#pragma unroll
  for (int rt = 0; rt < 2; ++rt) {
    float s = l[rt][0] + l[rt][1];
    s += __shfl_xor(s, 16);
    s += __shfl_xor(s, 32);
    float rl[4];
#pragma unroll
    for (int r = 0; r < 4; ++r) rl[r] = wgt / __shfl(s, lg * 4 + r);
#pragma unroll
    for (int dt = 0; dt < 4; ++dt)
#pragma unroll
      for (int r = 0; r < 4; ++r) total[rt][dt][r] += acc[rt][dt][r] * rl[r];
  }
}

__global__ __launch_bounds__(512) void attn_kernel(
    const unsigned short* __restrict__ Q,    // [B][S][H][512][64] pre-scaled
    const unsigned short* __restrict__ K,    // [B][S][H][512][64]
    const unsigned short* __restrict__ Vt,   // [B][S][H][64][512'] col-permuted
    const unsigned short* __restrict__ Vtd,  // [B][S][H][64][128'] col-permuted
    unsigned short* __restrict__ AO) {       // [B][S][H][512][64] head-major
  __shared__ unsigned short Kl[2 * 4096];
  __shared__ unsigned short Vl[2 * 4096];
  const int wg = blockIdx.x;   // 1024; blocks i and i+512 = same head -> same XCD
  const int qh = wg >> 9;
  const int bsh = wg & 511;
  const int h = bsh & 15, s = (bsh >> 4) & 15, b = bsh >> 8;
  const int t = threadIdx.x, w = t >> 6, lane = t & 63, lr = lane & 15, lg = lane >> 4;
  const int q0 = qh * 256 + w * 32;

  const size_t headbase = (size_t)((b * 16 + s) * 16 + h);
  const unsigned short* Qp = Q + headbase * 32768 + (size_t)q0 * 64;
  short8 qf[2][2];
#pragma unroll
  for (int rt = 0; rt < 2; ++rt)
#pragma unroll
    for (int ks = 0; ks < 2; ++ks)
      qf[rt][ks] = *reinterpret_cast<const short8*>(&Qp[(rt * 16 + lr) * 64 + ks * 32 + lg * 8]);

  f32x4 total[2][4];
#pragma unroll
  for (int rt = 0; rt < 2; ++rt)
#pragma unroll
    for (int dt = 0; dt < 4; ++dt) total[rt][dt] = f32x4{0.f, 0.f, 0.f, 0.f};

  // self segment (512 keys)
  attn_group(K + headbase * 32768, 64, Vt + headbase * 32768, 512, 8, 1.0f,
             qf, Kl, Vl, total, lr, lg, w, lane);
  // cross segments (dilated, 128 keys each, weight 0.25)
#pragma unroll
  for (int gi = 0; gi < 4; ++gi) {
    const int off = (gi == 0) ? -2 : (gi == 1) ? -1 : (gi == 2) ? 1 : 2;
    const int ns = s + off;
    if (ns < 0 || ns > 15) continue;
    const size_t hb = (size_t)((b * 16 + ns) * 16 + h);
    attn_group(K + hb * 32768, 256, Vtd + hb * 8192, 128, 2, 0.25f,
               qf, Kl, Vl, total, lr, lg, w, lane);
  }
  // store head-major: AO[headbase][q][d] — wave writes a contiguous 4KB block
  // (acc: q = q0 + rt*16 + lg*4 + r, d = dt*16 + lr)
  const size_t obase = headbase * 32768 + (size_t)q0 * 64;
#pragma unroll
  for (int rt = 0; rt < 2; ++rt)
#pragma unroll
    for (int dt = 0; dt < 4; ++dt)
#pragma unroll
      for (int r = 0; r < 4; ++r) {
        const int q = rt * 16 + lg * 4 + r;
        const int d = dt * 16 + lr;
        AO[obase + (size_t)q * 64 + d] = f2bf(total[rt][dt][r]);
      }
}

// ---------------- launch ----------------
extern "C" void kernel_launch(void* const* d_in, const int* in_sizes, int n_in,
                              void* d_out, int out_size, void* d_ws, size_t ws_size,
                              hipStream_t stream) {
  const float* x  = (const float*)d_in[0];
  const float* Wq = (const float*)d_in[1];
  const float* bq = (const float*)d_in[2];
  const float* Wk = (const float*)d_in[3];
  const float* bk = (const float*)d_in[4];
  const float* Wv = (const float*)d_in[5];
  const float* bv = (const float*)d_in[6];
  const float* Wo = (const float*)d_in[7];
  const float* bo = (const float*)d_in[8];
  float* out = (float*)d_out;

  char* ws = (char*)d_ws;
  unsigned short* Xb   = (unsigned short*)(ws);                 // 32 MiB
  unsigned short* Wqt  = (unsigned short*)(ws + 33554432);      // 2 MiB
  unsigned short* Wkt  = (unsigned short*)(ws + 35651584);
  unsigned short* Wvt  = (unsigned short*)(ws + 37748736);
  unsigned short* Wot  = (unsigned short*)(ws + 39845888);
  unsigned short* Qb   = (unsigned short*)(ws + 41943040);      // 32 MiB
  unsigned short* Kb   = (unsigned short*)(ws + 75497472);      // 32 MiB
  unsigned short* Vtb  = (unsigned short*)(ws + 109051904);     // 32 MiB
  unsigned short* Vtdb = (unsigned short*)(ws + 142606336);     // 8 MiB
  unsigned short* AOb  = (unsigned short*)(ws + 150994944);     // 32 MiB

  cast_x_kernel<<<8192, 256, 0, stream>>>(x, Xb, 2097152);
  dim3 tb(32, 8), tg(32, 32, 4);
  transpose_cast4_kernel<<<tg, tb, 0, stream>>>(Wq, Wk, Wv, Wo, Wqt, Wkt, Wvt, Wot);

  gemm_kernel<0><<<256, 512, 0, stream>>>(Xb, Wqt, bq, Qb, nullptr, nullptr);
  gemm_kernel<1><<<256, 512, 0, stream>>>(Xb, Wkt, bk, Kb, nullptr, nullptr);
  gemm_kernel<2><<<256, 512, 0, stream>>>(Xb, Wvt, bv, Vtb, Vtdb, nullptr);

  attn_kernel<<<1024, 512, 0, stream>>>(Qb, Kb, Vtb, Vtdb, AOb);

  gemm_kernel<3><<<256, 512, 0, stream>>>(AOb, Wot, bo, nullptr, nullptr, out);
}

// Round 13
// 285.247 us; speedup vs baseline: 1.0734x; 1.0734x over previous
//
#include <hip/hip_runtime.h>
#include <stdint.h>

typedef __attribute__((ext_vector_type(8))) short short8;
typedef __attribute__((ext_vector_type(4))) float f32x4;

#define MFMA16(A_, B_, C_) __builtin_amdgcn_mfma_f32_16x16x32_bf16((A_), (B_), (C_), 0, 0, 0)

#if __has_builtin(__builtin_amdgcn_exp2f)
#define EXP2(x) __builtin_amdgcn_exp2f(x)
#else
#define EXP2(x) exp2f(x)
#endif

// async global -> LDS, 16B per lane (dest = wave-uniform base + lane*16)
#define GLDS16(g_, l_)                                                        \
  __builtin_amdgcn_global_load_lds(                                           \
      (const __attribute__((address_space(1))) void*)(g_),                    \
      (__attribute__((address_space(3))) void*)(l_), 16, 0, 0)

__device__ __forceinline__ unsigned short f2bf(float f) {
  unsigned int u = __float_as_uint(f);
  u += 0x7fffu + ((u >> 16) & 1u);
  return (unsigned short)(u >> 16);
}

// pack two f32 -> two truncated bf16 in one u32 (a -> low, b -> high)
__device__ __forceinline__ unsigned pk2(float a, float b) {
  return (__float_as_uint(a) >> 16) | (__float_as_uint(b) & 0xffff0000u);
}

// ---------------- prep kernels ----------------

// 32B per thread: 8 floats -> 8 bf16 (RNE)
__global__ void cast_x_kernel(const float* __restrict__ x,
                              unsigned short* __restrict__ xb, int n8) {
  int i = blockIdx.x * blockDim.x + threadIdx.x;
  if (i >= n8) return;
  const float4* x4 = reinterpret_cast<const float4*>(x);
  float4 a = x4[2 * i], b = x4[2 * i + 1];
  uint4 o;
  o.x = (unsigned)f2bf(a.x) | ((unsigned)f2bf(a.y) << 16);
  o.y = (unsigned)f2bf(a.z) | ((unsigned)f2bf(a.w) << 16);
  o.z = (unsigned)f2bf(b.x) | ((unsigned)f2bf(b.y) << 16);
  o.w = (unsigned)f2bf(b.z) | ((unsigned)f2bf(b.w) << 16);
  reinterpret_cast<uint4*>(xb)[i] = o;
}

// Wt[n][k] = bf16(W[k][n]) for 4 weight matrices (blockIdx.z selects)
__global__ void transpose_cast4_kernel(const float* __restrict__ W0,
                                       const float* __restrict__ W1,
                                       const float* __restrict__ W2,
                                       const float* __restrict__ W3,
                                       unsigned short* __restrict__ T0,
                                       unsigned short* __restrict__ T1,
                                       unsigned short* __restrict__ T2,
                                       unsigned short* __restrict__ T3) {
  __shared__ float tile[32][33];
  const float* W = (blockIdx.z == 0) ? W0 : (blockIdx.z == 1) ? W1
                   : (blockIdx.z == 2) ? W2 : W3;
  unsigned short* Wt = (blockIdx.z == 0) ? T0 : (blockIdx.z == 1) ? T1
                       : (blockIdx.z == 2) ? T2 : T3;
  int k0 = blockIdx.x * 32, n0 = blockIdx.y * 32;
  int tx = threadIdx.x, ty = threadIdx.y;  // 32 x 8
  for (int i = ty; i < 32; i += 8)
    tile[i][tx] = W[(size_t)(k0 + i) * 1024 + n0 + tx];
  __syncthreads();
  for (int i = ty; i < 32; i += 8)
    Wt[(size_t)(n0 + i) * 1024 + k0 + tx] = f2bf(tile[tx][i]);
}

// ---------------- GEMM: 256x256 tile, BK=64, 8 waves, counted-vmcnt pipeline
// (r10-proven: ~37us/dispatch, ~930 TF — this 2-phase structure's ceiling)
// MODE 0: Q (scale by 0.125*log2e, store [b][s][h][r][d]); A = Xb [16384][1024]
// MODE 1: K (store [b][s][h][r][d]);                       A = Xb
// MODE 2: V (store Vt [b][s][h][d][r'] col-permuted + Vtd); A = Xb
// MODE 3: O (store f32 row-major to d_out); A = AO2 head-major [b][s][h][q][d]
//         (BK=64 == DK, so K-step kt == head index; A-tile for step kt is the
//          contiguous 32KB block AO2[head(b,s,kt)][q0..q0+256)[0..64))
// LDS layout: [buf][row][chunk], 16B chunk c holds global chunk c ^ (row&7).
template<int MODE>
__global__ __launch_bounds__(512, 2) void gemm_kernel(
    const unsigned short* __restrict__ A,
    const unsigned short* __restrict__ W,
    const float* __restrict__ bias,
    unsigned short* __restrict__ out_bf,
    unsigned short* __restrict__ out_vtd,
    float* __restrict__ out_f) {
  __shared__ unsigned short Asm[2][256 * 64];  // 64 KiB
  __shared__ unsigned short Bsm[2][256 * 64];  // 64 KiB
  const int t = threadIdx.x;
  // XCD-bijective swizzle (nwg = 256, %8 == 0)
  const int wg = (blockIdx.x & 7) * 32 + (blockIdx.x >> 3);
  const int m0 = (wg >> 2) * 256;
  const int n0 = (wg & 3) * 256;
  const int w = t >> 6, lane = t & 63, lr = lane & 15, lg = lane >> 4;
  const int wm = w >> 2, wn = w & 3;  // 2 x 4 wave grid; per-wave out 128x64

  f32x4 acc[8][4];
#pragma unroll
  for (int i = 0; i < 8; ++i)
#pragma unroll
    for (int j = 0; j < 4; ++j) acc[i][j] = f32x4{0.f, 0.f, 0.f, 0.f};

  // staging: wave w stages rows w*32 .. w*32+31 of both tiles.
  // lane -> row w*32 + p*8 + (lane>>3), source chunk = (lane&7) ^ (lane>>3).
  const int srow = lane >> 3;
  const int sswz = ((lane & 7) ^ srow) * 8;
  const int mrow = m0 + w * 32 + srow;
  const unsigned short* gA;
  size_t astep, arstride;  // per-kt advance, per-8-row advance
  if (MODE == 3) {
    // AO2 head-major: m = b*8192 + s*512 + q  ->  head base (m>>9), q = m&511
    gA = A + (size_t)(mrow >> 9) * (16 * 32768) + (size_t)(mrow & 511) * 64 + sswz;
    astep = 32768;       // next head
    arstride = 8 * 64;   // +8 q rows
  } else {
    gA = A + (size_t)mrow * 1024 + sswz;
    astep = 64;          // next 64 k-columns
    arstride = 8 * 1024; // +8 m rows
  }
  const unsigned short* gB = W + (size_t)(n0 + w * 32 + srow) * 1024 + sswz;

  auto stage = [&](int buf, int kt) {
    const unsigned short* ga = gA + (size_t)kt * astep;
    const unsigned short* gb = gB + (size_t)kt * 64;
    unsigned short* la = &Asm[buf][(w * 32) * 64];
    unsigned short* lb = &Bsm[buf][(w * 32) * 64];
#pragma unroll
    for (int p = 0; p < 4; ++p) {
      GLDS16(ga + (size_t)p * arstride, la + p * 8 * 64);
      GLDS16(gb + (size_t)(p * 8) * 1024, lb + p * 8 * 64);
    }
  };

  const int rswz = (lr & 7);  // read-side swizzle term (row&7 == lr&7)
  auto compute = [&](int buf) {
    const unsigned short* bA = &Asm[buf][0];
    const unsigned short* bB = &Bsm[buf][0];
    short8 bfv[2][4];
#pragma unroll
    for (int ks = 0; ks < 2; ++ks)
#pragma unroll
      for (int j = 0; j < 4; ++j) {
        const int row = wn * 64 + j * 16 + lr;
        bfv[ks][j] = *reinterpret_cast<const short8*>(
            &bB[row * 64 + (((ks * 4 + lg) ^ rswz) * 8)]);
      }
#pragma unroll
    for (int i = 0; i < 8; ++i) {
      const int row = wm * 128 + i * 16 + lr;
      short8 af[2];
#pragma unroll
      for (int ks = 0; ks < 2; ++ks)
        af[ks] = *reinterpret_cast<const short8*>(
            &bA[row * 64 + (((ks * 4 + lg) ^ rswz) * 8)]);
#pragma unroll
      for (int ks = 0; ks < 2; ++ks)
#pragma unroll
        for (int j = 0; j < 4; ++j)
          acc[i][j] = MFMA16(af[ks], bfv[ks][j], acc[i][j]);
    }
  };

  stage(0, 0);
#pragma unroll 1
  for (int kt = 0; kt < 15; ++kt) {
    stage((kt + 1) & 1, kt + 1);
    // own step-kt loads done; step-(kt+1)'s 8 stay in flight across barrier
    asm volatile("s_waitcnt vmcnt(8)\n\ts_barrier" ::: "memory");
    compute(kt & 1);
    asm volatile("s_waitcnt lgkmcnt(0)\n\ts_barrier" ::: "memory");
  }
  asm volatile("s_waitcnt vmcnt(0)\n\ts_barrier" ::: "memory");
  compute(1);  // kt = 15

#pragma unroll
  for (int i = 0; i < 8; ++i)
#pragma unroll
    for (int j = 0; j < 4; ++j) {
      const int n = n0 + wn * 64 + j * 16 + lr;
      const float bv = bias[n];
#pragma unroll
      for (int r = 0; r < 4; ++r) {
        const int m = m0 + wm * 128 + i * 16 + lg * 4 + r;
        float val = acc[i][j][r] + bv;
        if (MODE == 3) {
          out_f[(size_t)m * 1024 + n] = val;
        } else {
          const int b = m >> 13, ll = m & 8191;
          const int ss = ll >> 9, rr = ll & 511;
          const int hh = n >> 6, d = n & 63;
          const size_t head = (size_t)((b * 16 + ss) * 16 + hh);
          if (MODE == 0) {
            out_bf[head * 32768 + rr * 64 + d] = f2bf(val * 0.18033688011112042f);
          } else if (MODE == 1) {
            out_bf[head * 32768 + rr * 64 + d] = f2bf(val);
          } else {
            // column-permute within each 32-block: k = g*16+q*4+m -> pos = q*8+g*4+m
            const int p32 = (((rr >> 2) & 3) << 3) | (((rr >> 4) & 1) << 2) | (rr & 3);
            out_bf[head * 32768 + (size_t)d * 512 + ((rr & ~31) | p32)] = f2bf(val);
            if ((rr & 3) == 0) {
              const int cd = rr >> 2;
              const int pd = (((cd >> 2) & 3) << 3) | (((cd >> 4) & 1) << 2) | (cd & 3);
              out_vtd[head * 8192 + (size_t)d * 128 + ((cd & ~31) | pd)] = f2bf(val);
            }
          }
        }
      }
    }
}

// ---------------- attention ----------------
// r10-proven: grid 1024 (2 q-halves per head), 8 waves x 32 q-rows.
// Swapped QK^T (lane holds P[q=lr][k]), in-register P pack, permuted-k-slot PV.
// K/V chunk tiles (64x64 bf16) staged cooperatively (1 GLDS16 per wave each),
// double-buffered; __syncthreads() drains prefetch + protects buffer swap.
// Bank swizzle: LDS[row][c'] = G[row][c' ^ (row&7)] via pre-swizzled global
// source; reads XOR the same term (lr&7, lane-constant).
__device__ __forceinline__ void attn_group(
    const unsigned short* __restrict__ Kp, int kstride,   // 64 (self) / 256 (dil)
    const unsigned short* __restrict__ Vp, int vstride,   // 512 (self) / 128 (dil)
    int nchunks, float wgt,
    const short8 (&qf)[2][2],
    unsigned short* __restrict__ Kl, unsigned short* __restrict__ Vl,  // [2][4096]
    f32x4 (&total)[2][4],
    int lr, int lg, int w, int lane) {
  const int srow = lane >> 3;             // 0..7
  const int fcw = (lane & 7) ^ srow;      // swizzled fetch chunk
  const unsigned short* gK = Kp + (size_t)(w * 8 + srow) * kstride + fcw * 8;
  const unsigned short* gV = Vp + (size_t)(w * 8 + srow) * vstride + fcw * 8;
  const int sx = lr & 7;                  // read-side swizzle (chunks)

  float l[2][2] = {{0.f, 0.f}, {0.f, 0.f}};
  f32x4 acc[2][4];
#pragma unroll
  for (int rt = 0; rt < 2; ++rt)
#pragma unroll
    for (int dt = 0; dt < 4; ++dt) acc[rt][dt] = f32x4{0.f, 0.f, 0.f, 0.f};

  // prologue: stage chunk 0 -> buf 0
  GLDS16(gK, Kl + w * 512);
  GLDS16(gV, Vl + w * 512);
  __syncthreads();  // drains vmcnt(0): chunk 0 visible to all waves

  int cur = 0;
  for (int c = 0; c < nchunks; ++c) {
    if (c + 1 < nchunks) {  // prefetch next chunk into other buffer
      GLDS16(gK + (size_t)((c + 1) * 64) * kstride, Kl + (cur ^ 1) * 4096 + w * 512);
      GLDS16(gV + (c + 1) * 64, Vl + (cur ^ 1) * 4096 + w * 512);
    }
    const unsigned short* bK = Kl + cur * 4096;
    const unsigned short* bV = Vl + cur * 4096;

    short8 pf[2][2];
    // QK in kt-pairs (kp = ks of PV); sc live range = 16 regs
#pragma unroll
    for (int kp = 0; kp < 2; ++kp) {
      f32x4 s0[2], s1[2];
#pragma unroll
      for (int rt = 0; rt < 2; ++rt) {
        s0[rt] = f32x4{0.f, 0.f, 0.f, 0.f};
        s1[rt] = f32x4{0.f, 0.f, 0.f, 0.f};
      }
      __builtin_amdgcn_s_setprio(1);
#pragma unroll
      for (int ks = 0; ks < 2; ++ks) {
        const int rc = (((ks * 4 + lg) ^ sx) * 8);
        short8 kf0 = *reinterpret_cast<const short8*>(&bK[(kp * 32 + lr) * 64 + rc]);
        short8 kf1 = *reinterpret_cast<const short8*>(&bK[(kp * 32 + 16 + lr) * 64 + rc]);
#pragma unroll
        for (int rt = 0; rt < 2; ++rt) {
          s0[rt] = MFMA16(kf0, qf[rt][ks], s0[rt]);
          s1[rt] = MFMA16(kf1, qf[rt][ks], s1[rt]);
        }
      }
      __builtin_amdgcn_s_setprio(0);
#pragma unroll
      for (int rt = 0; rt < 2; ++rt) {
        float e0 = EXP2(s0[rt][0]), e1 = EXP2(s0[rt][1]);
        float e2 = EXP2(s0[rt][2]), e3 = EXP2(s0[rt][3]);
        float e4 = EXP2(s1[rt][0]), e5 = EXP2(s1[rt][1]);
        float e6 = EXP2(s1[rt][2]), e7 = EXP2(s1[rt][3]);
        l[rt][kp] += ((e0 + e1) + (e2 + e3)) + ((e4 + e5) + (e6 + e7));
        uint4 wv;
        wv.x = pk2(e0, e1); wv.y = pk2(e2, e3);
        wv.z = pk2(e4, e5); wv.w = pk2(e6, e7);
        pf[rt][kp] = *reinterpret_cast<short8*>(&wv);
      }
    }
    // PV (V columns pre-permuted at GEMM store -> 16B contiguous fragments)
    __builtin_amdgcn_s_setprio(1);
#pragma unroll
    for (int ks = 0; ks < 2; ++ks) {
      const int rcv = (((ks * 4 + lg) ^ sx) * 8);
#pragma unroll
      for (int dt = 0; dt < 4; ++dt) {
        short8 vf = *reinterpret_cast<const short8*>(&bV[(dt * 16 + lr) * 64 + rcv]);
#pragma unroll
        for (int rt = 0; rt < 2; ++rt)
          acc[rt][dt] = MFMA16(pf[rt][ks], vf, acc[rt][dt]);
      }
    }
    __builtin_amdgcn_s_setprio(0);
    __syncthreads();  // drains prefetch (vmcnt 0) + protects buffer swap
    cur ^= 1;
  }
  // finalize: l full sum at q=lr; acc rows q=lg*4+r -> transpose l via shfl
#pragma unroll
  for (int rt = 0; rt < 2; ++rt) {
    float s = l[rt][0] + l[rt][1];
    s += __shfl_xor(s, 16);
    s += __shfl_xor(s, 32);
    float rl[4];
#pragma unroll
    for (int r = 0; r < 4; ++r) rl[r] = wgt / __shfl(s, lg * 4 + r);
#pragma unroll
    for (int dt = 0; dt < 4; ++dt)
#pragma unroll
      for (int r = 0; r < 4; ++r) total[rt][dt][r] += acc[rt][dt][r] * rl[r];
  }
}

__global__ __launch_bounds__(512) void attn_kernel(
    const unsigned short* __restrict__ Q,    // [B][S][H][512][64] pre-scaled
    const unsigned short* __restrict__ K,    // [B][S][H][512][64]
    const unsigned short* __restrict__ Vt,   // [B][S][H][64][512'] col-permuted
    const unsigned short* __restrict__ Vtd,  // [B][S][H][64][128'] col-permuted
    unsigned short* __restrict__ AO) {       // [B][S][H][512][64] head-major
  __shared__ unsigned short Kl[2 * 4096];
  __shared__ unsigned short Vl[2 * 4096];
  const int wg = blockIdx.x;  // 1024 = 512 bsh * 2 q-halves
  const int qh = wg & 1;
  const int bsh = wg >> 1;
  const int h = bsh & 15, s = (bsh >> 4) & 15, b = bsh >> 8;
  const int t = threadIdx.x, w = t >> 6, lane = t & 63, lr = lane & 15, lg = lane >> 4;
  const int q0 = qh * 256 + w * 32;

  const size_t headbase = (size_t)((b * 16 + s) * 16 + h);
  const unsigned short* Qp = Q + headbase * 32768 + (size_t)q0 * 64;
  short8 qf[2][2];
#pragma unroll
  for (int rt = 0; rt < 2; ++rt)
#pragma unroll
    for (int ks = 0; ks < 2; ++ks)
      qf[rt][ks] = *reinterpret_cast<const short8*>(&Qp[(rt * 16 + lr) * 64 + ks * 32 + lg * 8]);

  f32x4 total[2][4];
#pragma unroll
  for (int rt = 0; rt < 2; ++rt)
#pragma unroll
    for (int dt = 0; dt < 4; ++dt) total[rt][dt] = f32x4{0.f, 0.f, 0.f, 0.f};

  // self segment (512 keys)
  attn_group(K + headbase * 32768, 64, Vt + headbase * 32768, 512, 8, 1.0f,
             qf, Kl, Vl, total, lr, lg, w, lane);
  // cross segments (dilated, 128 keys each, weight 0.25)
#pragma unroll
  for (int gi = 0; gi < 4; ++gi) {
    const int off = (gi == 0) ? -2 : (gi == 1) ? -1 : (gi == 2) ? 1 : 2;
    const int ns = s + off;
    if (ns < 0 || ns > 15) continue;
    const size_t hb = (size_t)((b * 16 + ns) * 16 + h);
    attn_group(K + hb * 32768, 256, Vtd + hb * 8192, 128, 2, 0.25f,
               qf, Kl, Vl, total, lr, lg, w, lane);
  }
  // store head-major: AO[headbase][q][d] — wave writes a contiguous 4KB block
  // (acc: q = q0 + rt*16 + lg*4 + r, d = dt*16 + lr)
  const size_t obase = headbase * 32768 + (size_t)q0 * 64;
#pragma unroll
  for (int rt = 0; rt < 2; ++rt)
#pragma unroll
    for (int dt = 0; dt < 4; ++dt)
#pragma unroll
      for (int r = 0; r < 4; ++r) {
        const int q = rt * 16 + lg * 4 + r;
        const int d = dt * 16 + lr;
        AO[obase + (size_t)q * 64 + d] = f2bf(total[rt][dt][r]);
      }
}

// ---------------- launch ----------------
extern "C" void kernel_launch(void* const* d_in, const int* in_sizes, int n_in,
                              void* d_out, int out_size, void* d_ws, size_t ws_size,
                              hipStream_t stream) {
  const float* x  = (const float*)d_in[0];
  const float* Wq = (const float*)d_in[1];
  const float* bq = (const float*)d_in[2];
  const float* Wk = (const float*)d_in[3];
  const float* bk = (const float*)d_in[4];
  const float* Wv = (const float*)d_in[5];
  const float* bv = (const float*)d_in[6];
  const float* Wo = (const float*)d_in[7];
  const float* bo = (const float*)d_in[8];
  float* out = (float*)d_out;

  char* ws = (char*)d_ws;
  unsigned short* Xb   = (unsigned short*)(ws);                 // 32 MiB
  unsigned short* Wqt  = (unsigned short*)(ws + 33554432);      // 2 MiB
  unsigned short* Wkt  = (unsigned short*)(ws + 35651584);
  unsigned short* Wvt  = (unsigned short*)(ws + 37748736);
  unsigned short* Wot  = (unsigned short*)(ws + 39845888);
  unsigned short* Qb   = (unsigned short*)(ws + 41943040);      // 32 MiB
  unsigned short* Kb   = (unsigned short*)(ws + 75497472);      // 32 MiB
  unsigned short* Vtb  = (unsigned short*)(ws + 109051904);     // 32 MiB
  unsigned short* Vtdb = (unsigned short*)(ws + 142606336);     // 8 MiB
  unsigned short* AOb  = (unsigned short*)(ws + 150994944);     // 32 MiB

  cast_x_kernel<<<8192, 256, 0, stream>>>(x, Xb, 2097152);
  dim3 tb(32, 8), tg(32, 32, 4);
  transpose_cast4_kernel<<<tg, tb, 0, stream>>>(Wq, Wk, Wv, Wo, Wqt, Wkt, Wvt, Wot);

  gemm_kernel<0><<<256, 512, 0, stream>>>(Xb, Wqt, bq, Qb, nullptr, nullptr);
  gemm_kernel<1><<<256, 512, 0, stream>>>(Xb, Wkt, bk, Kb, nullptr, nullptr);
  gemm_kernel<2><<<256, 512, 0, stream>>>(Xb, Wvt, bv, Vtb, Vtdb, nullptr);

  attn_kernel<<<1024, 512, 0, stream>>>(Qb, Kb, Vtb, Vtdb, AOb);

  gemm_kernel<3><<<256, 512, 0, stream>>>(AOb, Wot, bo, nullptr, nullptr, out);
}